// Round 11
// baseline (521.696 us; speedup 1.0000x reference)
//
#include <hip/hip_runtime.h>

// Problem dims
#define BB 16
#define SS 96
#define KK 10
#define FF 256
#define IH 64
#define IW 64
#define OCH 32
#define PH 31
#define PW 31
#define NPOS 961          // 31*31
#define FDIM 30752        // 32*961
#define NIMG 1536         // 16*96

// Solver hyper-params
#define TAUI 20.0f        // 1/TAU
#define RHOC 10.0f
#define LRC  0.5f
#define NSTEPS 60

// fc_gemm split-K: 30752 = 31 * 992, 992 = 31 k-steps of 32
#define KSPLIT 31
#define KCHE 992

// prep kernel grid split: first NIMG blocks = conv, rest = fc-weight cast
#define WCBLK ((FF * FDIM) / 1024)   // 7688

typedef _Float16 v8hf __attribute__((ext_vector_type(8)));
typedef _Float16 v4hf __attribute__((ext_vector_type(4)));
typedef __fp16 h2 __attribute__((ext_vector_type(2)));
typedef float v4f __attribute__((ext_vector_type(4)));

// ---------------- K1: fused prep ----------------
// blocks [0, NIMG): conv3x3+bias+relu+maxpool via MFMA 16x16x32 f16 (implicit GEMM)
// blocks [NIMG, NIMG+WCBLK): fc weight fp32->fp16 cast (overlaps with conv).
__global__ __launch_bounds__(256)
void prep(const float* __restrict__ X, const float* __restrict__ convw,
          const float* __restrict__ bias, _Float16* __restrict__ pooled,
          const float* __restrict__ fcw, _Float16* __restrict__ wh) {
    const int tid = threadIdx.x;
    if (blockIdx.x >= NIMG) {
        // ---- wcast part ----
        const size_t i = ((size_t)(blockIdx.x - NIMG) * 256 + tid) * 4;
        float4 v = *(const float4*)(fcw + i);
        v4hf o = {(_Float16)v.x, (_Float16)v.y, (_Float16)v.z, (_Float16)v.w};
        *(v4hf*)(wh + i) = o;
        return;
    }
    // ---- conv part: one block per image ----
    __shared__ _Float16 Xl[3 * 64 * 64 + 256];   // fp16 planes + pad (OOB-safe reads)
    __shared__ _Float16 Wl[32 * 32];             // [oc][k], k padded to 32 with zeros
    const int img = blockIdx.x;
    const float* xb = X + (size_t)img * (3 * IH * IW);
#pragma unroll
    for (int i = 0; i < 12; i++) {
        const int e = tid + i * 256;             // float4 index 0..3071
        float4 v = *(const float4*)(xb + (size_t)e * 4);
        h2 p0 = __builtin_amdgcn_cvt_pkrtz(v.x, v.y);   // same RTZ as old kernel
        h2 p1 = __builtin_amdgcn_cvt_pkrtz(v.z, v.w);
        *(h2*)&Xl[e * 4] = p0;
        *(h2*)&Xl[e * 4 + 2] = p1;
    }
    for (int t = tid; t < 1024; t += 256) {
        const int oc = t >> 5, k = t & 31;
        Wl[t] = (k < 27) ? (_Float16)convw[oc * 27 + k] : (_Float16)0.f;
    }
    __syncthreads();

    const int lane = tid & 63;
    const int l16 = lane & 15, q = lane >> 4;
    const int wv = tid >> 6;                     // wave 0..3
    // weight fragments: lane l16 = oc row, k = q*8+j
    v8hf a0 = *(const v8hf*)&Wl[l16 * 32 + q * 8];
    v8hf a1 = *(const v8hf*)&Wl[(16 + l16) * 32 + q * 8];
    // per-lane k -> LDS offset table (static indices only)
    int off[8];
#pragma unroll
    for (int j = 0; j < 8; j++) {
        const int k = q * 8 + j;
        const int c = k / 9, rem = k - c * 9;
        const int ky = rem / 3, kx = rem - ky * 3;
        off[j] = c * 4096 + ky * 64 + kx;        // k>=27 -> lands in pad region
    }
    const bool hi_ok = (q < 3);                  // j>=3 valid only for quads 0..2
    float b0r[4], b1r[4];
#pragma unroll
    for (int i = 0; i < 4; i++) {
        b0r[i] = bias[q * 4 + i];
        b1r[i] = bias[16 + q * 4 + i];
    }
    _Float16* outp = pooled + (size_t)img * FDIM;

    for (int oy = wv; oy < PH; oy += 4) {
        const int y0 = oy * 2;
#pragma unroll
        for (int xt = 0; xt < 4; xt++) {
            const int x = xt * 16 + l16;
            const int base0 = y0 * 64 + x;
            v8hf bf0, bf1;
#pragma unroll
            for (int j = 0; j < 8; j++) {
                _Float16 h0 = Xl[base0 + off[j]];
                _Float16 h1 = Xl[base0 + 64 + off[j]];
                if (j >= 3 && !hi_ok) { h0 = (_Float16)0.f; h1 = (_Float16)0.f; }
                bf0[j] = h0; bf1[j] = h1;
            }
            v4f c00 = (v4f)(0.f), c10 = (v4f)(0.f), c01 = (v4f)(0.f), c11 = (v4f)(0.f);
            c00 = __builtin_amdgcn_mfma_f32_16x16x32_f16(a0, bf0, c00, 0, 0, 0);
            c10 = __builtin_amdgcn_mfma_f32_16x16x32_f16(a1, bf0, c10, 0, 0, 0);
            c01 = __builtin_amdgcn_mfma_f32_16x16x32_f16(a0, bf1, c01, 0, 0, 0);
            c11 = __builtin_amdgcn_mfma_f32_16x16x32_f16(a1, bf1, c11, 0, 0, 0);
            const int ox = xt * 8 + (l16 >> 1);
            const bool act = ((l16 & 1) == 0) && (ox < PW);
#pragma unroll
            for (int i = 0; i < 4; i++) {
                float m0 = fmaxf(c00[i], c01[i]);          // y-pool, oc tile 0
                float m1 = fmaxf(c10[i], c11[i]);          // y-pool, oc tile 1
                m0 = fmaxf(m0, __shfl_xor(m0, 1));         // x-pool
                m1 = fmaxf(m1, __shfl_xor(m1, 1));
                if (act) {
                    const int oc0 = q * 4 + i;
                    const float r0 = fmaxf(m0 + b0r[i], 0.f);
                    const float r1 = fmaxf(m1 + b1r[i], 0.f);
                    outp[(size_t)oc0 * NPOS + oy * PW + ox] = (_Float16)r0;
                    outp[(size_t)(16 + oc0) * NPOS + oy * PW + ox] = (_Float16)r1;
                }
            }
        }
    }
}

// ---------------- K2: FC GEMM fp16 MFMA, 128x128 tile, split-K=31, EXPLICIT prefetch pipeline ----------------
// Hypothesis test (R11): R3 assumed the compiler hoists next-step global loads
// across the barrier pair; non-ot time accounting (fc_gemm ~150-190us by
// elimination = ~130-160 TF, 3-4x below the reg-staged 128^2 class) suggests it
// does NOT, leaving each k-step serially exposed to a full L3 round-trip.
// This version loads step s+1's registers BY SOURCE ORDER after the second
// barrier, before step s's ds_read+MFMA — guaranteeing loads are in flight
// during compute regardless of compiler barrier conservatism.
// Arithmetic order / LDS layout / output: bitwise identical to the proven kernel.
__global__ __launch_bounds__(256)
void fc_gemm(const _Float16* __restrict__ Ah, const _Float16* __restrict__ Wh,
             float* __restrict__ fpart) {
    __shared__ _Float16 Asl[128 * 56];
    __shared__ _Float16 Bsl[128 * 56];
    const int m0 = blockIdx.x * 128, n0 = blockIdx.y * 128;
    const int k0 = blockIdx.z * KCHE;
    const int tid = threadIdx.x;
    const int wave = tid >> 6, lane = tid & 63;
    const int quad = lane >> 4, l16 = lane & 15;
    const int wm = (wave & 1) * 64, wn = (wave >> 1) * 64;
    const int ar = tid >> 1, ac = (tid & 1) * 16;   // row 0..127, halves [ac,ac+16)
    const _Float16* Ag = Ah + (size_t)(m0 + ar) * FDIM + ac;
    const _Float16* Bg = Wh + (size_t)(n0 + ar) * FDIM + ac;

    v4f acc[4][4];
#pragma unroll
    for (int i = 0; i < 4; i++)
#pragma unroll
        for (int j = 0; j < 4; j++) acc[i][j] = (v4f)(0.f);

    // prologue: loads for s=0
    uint4 a0 = *(const uint4*)(Ag + k0);
    uint4 a1 = *(const uint4*)(Ag + k0 + 8);
    uint4 b0 = *(const uint4*)(Bg + k0);
    uint4 b1 = *(const uint4*)(Bg + k0 + 8);

    for (int s = 0; s < KCHE / 32; s++) {
        __syncthreads();
        *(uint4*)&Asl[ar * 56 + ac] = a0;
        *(uint4*)&Asl[ar * 56 + ac + 8] = a1;
        *(uint4*)&Bsl[ar * 56 + ac] = b0;
        *(uint4*)&Bsl[ar * 56 + ac + 8] = b1;
        __syncthreads();
        // issue NEXT step's loads now: in flight during ds_read + MFMA below
        uint4 a0n, a1n, b0n, b1n;
        if (s < KCHE / 32 - 1) {
            const int gk = k0 + ((s + 1) << 5);
            a0n = *(const uint4*)(Ag + gk);
            a1n = *(const uint4*)(Ag + gk + 8);
            b0n = *(const uint4*)(Bg + gk);
            b1n = *(const uint4*)(Bg + gk + 8);
        }
        v8hf af[4], bf[4];
#pragma unroll
        for (int mt = 0; mt < 4; mt++)
            af[mt] = *(const v8hf*)&Asl[(wm + mt * 16 + l16) * 56 + quad * 8];
#pragma unroll
        for (int nt = 0; nt < 4; nt++)
            bf[nt] = *(const v8hf*)&Bsl[(wn + nt * 16 + l16) * 56 + quad * 8];
#pragma unroll
        for (int mt = 0; mt < 4; mt++)
#pragma unroll
            for (int nt = 0; nt < 4; nt++)
                acc[mt][nt] = __builtin_amdgcn_mfma_f32_16x16x32_f16(
                    af[mt], bf[nt], acc[mt][nt], 0, 0, 0);
        a0 = a0n; a1 = a1n; b0 = b0n; b1 = b1n;   // rotate (dead on last iter)
    }
    float* outz = fpart + (size_t)blockIdx.z * NIMG * FF;
#pragma unroll
    for (int mt = 0; mt < 4; mt++)
#pragma unroll
        for (int nt = 0; nt < 4; nt++)
#pragma unroll
            for (int i = 0; i < 4; i++) {
                const int gm = m0 + wm + mt * 16 + quad * 4 + i;
                const int gn = n0 + wn + nt * 16 + l16;
                outz[(size_t)gm * FF + gn] = acc[mt][nt][i];
            }
}

// ---------------- K2b: sum 31 split-K partials + bias + relu + fused row-norms ----------------
__global__ __launch_bounds__(256)
void bias_sum_relu(const float* __restrict__ fpart, const float* __restrict__ bias,
                   float* __restrict__ f, float* __restrict__ n2) {
    const int tid = threadIdx.x;
    const size_t idx = ((size_t)blockIdx.x * 256 + tid) * 4;
    float4 s = make_float4(0.f, 0.f, 0.f, 0.f);
#pragma unroll
    for (int z = 0; z < KSPLIT; z++) {
        float4 v = *(const float4*)(fpart + (size_t)z * NIMG * FF + idx);
        s.x += v.x; s.y += v.y; s.z += v.z; s.w += v.w;
    }
    const int col = (int)(idx & (FF - 1));
    float4 bv = *(const float4*)(bias + col);
    float4 o;
    o.x = fmaxf(s.x + bv.x, 0.f);
    o.y = fmaxf(s.y + bv.y, 0.f);
    o.z = fmaxf(s.z + bv.z, 0.f);
    o.w = fmaxf(s.w + bv.w, 0.f);
    *(float4*)(f + idx) = o;
    // fused rownorm: wave w of this block owns row blockIdx.x*4 + w
    float sq = o.x * o.x + o.y * o.y + o.z * o.z + o.w * o.w;
#pragma unroll
    for (int mm = 32; mm >= 1; mm >>= 1) sq += __shfl_xor(sq, mm);
    if ((tid & 63) == 0) n2[blockIdx.x * 4 + (tid >> 6)] = sq;
}

// ---------------- K3b: D = clamp(n2_i + n2_j - 2<f_i,f_j>, 0) ----------------
__global__ __launch_bounds__(256)
void dmat(const float* __restrict__ feats, const float* __restrict__ n2,
          float* __restrict__ Dm) {
    const int i0 = blockIdx.x * 16, j0 = blockIdx.y * 16, b = blockIdx.z;
    __shared__ float fi[16][260], fj[16][260];
    const int tid = threadIdx.x;
    const int r = tid >> 4, c0 = (tid & 15) * 16;
    const float* fbase = feats + (size_t)b * SS * FF;
#pragma unroll
    for (int v = 0; v < 16; v += 4) {
        float4 a = *(const float4*)(fbase + (size_t)(i0 + r) * FF + c0 + v);
        float4 w = *(const float4*)(fbase + (size_t)(j0 + r) * FF + c0 + v);
        *(float4*)&fi[r][c0 + v] = a;
        *(float4*)&fj[r][c0 + v] = w;
    }
    __syncthreads();
    const int ti = tid >> 4, tj = tid & 15;
    float dot = 0.f;
#pragma unroll 4
    for (int f = 0; f < FF; f += 4) {
        float4 a = *(const float4*)&fi[ti][f];
        float4 w = *(const float4*)&fj[tj][f];
        dot += a.x * w.x + a.y * w.y + a.z * w.z + a.w * w.w;
    }
    const int i = i0 + ti, j = j0 + tj;
    const float d = n2[b * SS + i] + n2[b * SS + j] - 2.f * dot;
    Dm[((size_t)b * SS + i) * SS + j] = fmaxf(d, 0.f);
}

// ---------------- K4: robust-OT solve, v9 (PROVEN 269.5us): R6 XCD-colocation + 3-barrier collect/publish ----------------
// Protocol converged after 6 variants (counter RMW + 1-line poll + bulk read;
// XCD-colocated mapping; merged collect+publish). Do not touch.
__global__ __launch_bounds__(512)
void ot_kernel(const float* __restrict__ Dg, const float* __restrict__ Qg,
               const float* __restrict__ thetag, float* __restrict__ ppub,
               unsigned* __restrict__ bar, float* __restrict__ out) {
    const int bk = blockIdx.x;
    const int b = bk % BB, k = bk / BB;      // XCD-colocating remap (R6, proven)
    const int tid = threadIdx.x;
    const int hw = tid >> 5, l = tid & 31;

    __shared__ float ppart[16][SS];
    __shared__ float cpart[16];
    __shared__ float Msh[SS];
    __shared__ float pown[SS];
    __shared__ float lamsh;

    float a[6][3], e[6][3], dre[6][3], rz[6], qi[6];

    const float* Db = Dg + (size_t)b * SS * SS;
    const float* Qb = Qg + ((size_t)b * KK + k) * SS;
#pragma unroll
    for (int r = 0; r < 6; r++) {
        const int i = hw * 6 + r;
#pragma unroll
        for (int u = 0; u < 3; u++) dre[r][u] = Db[i * SS + l + 32 * u];
        qi[r] = Qb[i];
    }
    const float th = thetag[k];
    unsigned* ctr = bar + b * 64;
    unsigned target = 0;

    // collect partials into pown, publish into buffer `buf`, drain, close barrier.
    auto collect_publish = [&](int buf) {
        __syncthreads();
        if (tid < SS) {
            float s = 0.f;
#pragma unroll
            for (int h = 0; h < 16; h++) s += ppart[h][tid];
            pown[tid] = s;
            __hip_atomic_store(&ppub[(((size_t)buf * BB + b) * KK + k) * SS + tid],
                               s, __ATOMIC_RELAXED, __HIP_MEMORY_SCOPE_AGENT);
        }
        if (tid == 0) {
            float c = 0.f;
#pragma unroll
            for (int h = 0; h < 16; h++) c += cpart[h];
            lamsh = 2.f * RHOC * fmaxf(c - th, 0.f);
        }
        asm volatile("s_waitcnt vmcnt(0)" ::: "memory");   // drain publish stores
        __syncthreads();                                    // all waves drained
    };

    // announce arrival + wait for all 10 blocks of this b-group.
    auto wait_group = [&]() {
        target += KK;
        if (tid == 0) {
            __hip_atomic_fetch_add(ctr, 1u, __ATOMIC_RELAXED, __HIP_MEMORY_SCOPE_AGENT);
            while (__hip_atomic_load(ctr, __ATOMIC_RELAXED, __HIP_MEMORY_SCOPE_AGENT) < target)
                __builtin_amdgcn_s_sleep(2);
        }
        __syncthreads();
    };

    {
        float cd[6];
#pragma unroll
        for (int r = 0; r < 6; r++) {
#pragma unroll
            for (int u = 0; u < 3; u++) { a[r][u] = 0.f; e[r][u] = 1.f; }
            rz[r] = 1.f / 96.f;
            cd[r] = dre[r][0] + dre[r][1] + dre[r][2];
        }
#pragma unroll
        for (int mm = 16; mm >= 1; mm >>= 1)
#pragma unroll
            for (int r = 0; r < 6; r++) cd[r] += __shfl_xor(cd[r], mm);
        float pp0 = 0.f, cc = 0.f;
#pragma unroll
        for (int r = 0; r < 6; r++) {
            const float scale = qi[r] * rz[r];
            pp0 += scale;
            cc += scale * cd[r];
        }
        ppart[hw][l] = pp0; ppart[hw][l + 32] = pp0; ppart[hw][l + 64] = pp0;
        if (l == 0) cpart[hw] = cc;
        collect_publish(0);
        wait_group();
    }

    for (int t = 0; t < NSTEPS; t++) {
        const int rbuf = t & 1;
        if (tid < SS) {
            const float* ps = ppub + (((size_t)rbuf * BB + b) * KK) * SS + tid;
            float v[KK];
            float mx = -1e30f;
#pragma unroll
            for (int kk2 = 0; kk2 < KK; kk2++) {
                v[kk2] = __hip_atomic_load(&ps[kk2 * SS], __ATOMIC_RELAXED,
                                           __HIP_MEMORY_SCOPE_AGENT) * TAUI;
                mx = fmaxf(mx, v[kk2]);
            }
            float sum = 0.f;
#pragma unroll
            for (int kk2 = 0; kk2 < KK; kk2++) sum += __expf(v[kk2] - mx);
            Msh[tid] = __expf(v[k] - mx) * __builtin_amdgcn_rcpf(sum);
        }
        __syncthreads();
        const float lam = lamsh;
        const float M0 = Msh[l], M1 = Msh[l + 32], M2 = Msh[l + 64];

        float g[6][3], dt[6];
#pragma unroll
        for (int r = 0; r < 6; r++) {
            g[r][0] = fmaf(lam, dre[r][0], M0);
            g[r][1] = fmaf(lam, dre[r][1], M1);
            g[r][2] = fmaf(lam, dre[r][2], M2);
            dt[r] = (e[r][0] * g[r][0] + e[r][1] * g[r][1] + e[r][2] * g[r][2]) * rz[r];
        }
#pragma unroll
        for (int mm = 16; mm >= 1; mm >>= 1)
#pragma unroll
            for (int r = 0; r < 6; r++) dt[r] += __shfl_xor(dt[r], mm);

        float mrow[6];
#pragma unroll
        for (int r = 0; r < 6; r++) {
            const float cq = LRC * qi[r] * rz[r];
            a[r][0] -= cq * e[r][0] * (g[r][0] - dt[r]);
            a[r][1] -= cq * e[r][1] * (g[r][1] - dt[r]);
            a[r][2] -= cq * e[r][2] * (g[r][2] - dt[r]);
            mrow[r] = fmaxf(a[r][0], fmaxf(a[r][1], a[r][2]));
        }
#pragma unroll
        for (int mm = 16; mm >= 1; mm >>= 1)
#pragma unroll
            for (int r = 0; r < 6; r++) mrow[r] = fmaxf(mrow[r], __shfl_xor(mrow[r], mm));

        float zz[6], cd[6];
#pragma unroll
        for (int r = 0; r < 6; r++) {
            e[r][0] = __expf(a[r][0] - mrow[r]);
            e[r][1] = __expf(a[r][1] - mrow[r]);
            e[r][2] = __expf(a[r][2] - mrow[r]);
            zz[r] = e[r][0] + e[r][1] + e[r][2];
            cd[r] = e[r][0] * dre[r][0] + e[r][1] * dre[r][1] + e[r][2] * dre[r][2];
        }
#pragma unroll
        for (int mm = 16; mm >= 1; mm >>= 1)
#pragma unroll
            for (int r = 0; r < 6; r++) {
                zz[r] += __shfl_xor(zz[r], mm);
                cd[r] += __shfl_xor(cd[r], mm);
            }

        float pp0 = 0.f, pp1 = 0.f, pp2 = 0.f, cc = 0.f;
#pragma unroll
        for (int r = 0; r < 6; r++) {
            const float rzz = __builtin_amdgcn_rcpf(zz[r]);
            rz[r] = rzz;
            const float scale = qi[r] * rzz;
            pp0 += scale * e[r][0];
            pp1 += scale * e[r][1];
            pp2 += scale * e[r][2];
            cc += scale * cd[r];
        }
        ppart[hw][l] = pp0; ppart[hw][l + 32] = pp1; ppart[hw][l + 64] = pp2;
        if (l == 0) cpart[hw] = cc;
        collect_publish((t + 1) & 1);   // final iter's store is dead but harmless
        if (t < NSTEPS - 1) wait_group();
    }
    if (tid < SS) out[((size_t)b * KK + k) * SS + tid] = pown[tid];
}

// ---------------- launch ----------------
extern "C" void kernel_launch(void* const* d_in, const int* in_sizes, int n_in,
                              void* d_out, int out_size, void* d_ws, size_t ws_size,
                              hipStream_t stream) {
    const float* X     = (const float*)d_in[0];
    const float* Q     = (const float*)d_in[1];
    const float* convw = (const float*)d_in[2];
    const float* convb = (const float*)d_in[3];
    const float* fcw   = (const float*)d_in[4];
    const float* fcb   = (const float*)d_in[5];
    const float* theta = (const float*)d_in[6];
    float* out = (float*)d_out;

    char* ws = (char*)d_ws;
    size_t off = 0;
    auto take = [&](size_t nbytes) {
        char* p = ws + off;
        off += (nbytes + 255) & ~(size_t)255;
        return (void*)p;
    };
    _Float16* pooled = (_Float16*)take((size_t)NIMG * FDIM * 2);       // 94.5 MB
    _Float16* Wh     = (_Float16*)take((size_t)FF * FDIM * 2);         // 15.7 MB
    float*    fpart  = (float*)take((size_t)KSPLIT * NIMG * FF * 4);   // 48.8 MB
    float*    feats  = (float*)take((size_t)NIMG * FF * 4);
    float*    n2     = (float*)take((size_t)NIMG * 4);
    float*    Dm     = (float*)take((size_t)BB * SS * SS * 4);
    float*    ppub   = (float*)take((size_t)2 * BB * KK * SS * 4);
    unsigned* bar    = (unsigned*)take((size_t)BB * 64 * 4);

    (void)hipMemsetAsync(bar, 0, (size_t)BB * 64 * 4, stream);

    hipLaunchKernelGGL(prep, dim3(NIMG + WCBLK), dim3(256), 0, stream,
                       X, convw, convb, pooled, fcw, Wh);
    hipLaunchKernelGGL(fc_gemm, dim3(12, 2, KSPLIT), dim3(256), 0, stream, pooled, Wh, fpart);
    hipLaunchKernelGGL(bias_sum_relu, dim3(NIMG * FF / 1024), dim3(256), 0, stream,
                       fpart, fcb, feats, n2);
    hipLaunchKernelGGL(dmat, dim3(6, 6, BB), dim3(256), 0, stream, feats, n2, Dm);
    hipLaunchKernelGGL(ot_kernel, dim3(BB * KK), dim3(512), 0, stream, Dm, Q, theta, ppub, bar, out);
}

// Round 12
// 508.388 us; speedup vs baseline: 1.0262x; 1.0262x over previous
//
#include <hip/hip_runtime.h>

// Problem dims
#define BB 16
#define SS 96
#define KK 10
#define FF 256
#define IH 64
#define IW 64
#define OCH 32
#define PH 31
#define PW 31
#define NPOS 961          // 31*31
#define FDIM 30752        // 32*961
#define NIMG 1536         // 16*96

// Solver hyper-params
#define TAUI 20.0f        // 1/TAU
#define RHOC 10.0f
#define LRC  0.5f
#define NSTEPS 60

// fc_gemm split-K: 30752 = 31 * 992, 992 = 31 k-steps of 32
#define KSPLIT 31
#define KCHE 992
#define FCGRID 752        // 8-padded grid for XCD pair-swizzle (372 (x,z) pairs x 2 y)

// prep kernel grid split: first NIMG blocks = conv, rest = fc-weight cast
#define WCBLK ((FF * FDIM) / 1024)   // 7688

typedef _Float16 v8hf __attribute__((ext_vector_type(8)));
typedef _Float16 v4hf __attribute__((ext_vector_type(4)));
typedef __fp16 h2 __attribute__((ext_vector_type(2)));
typedef float v4f __attribute__((ext_vector_type(4)));

// ---------------- K1: fused prep ----------------
// blocks [0, NIMG): conv3x3+bias+relu+maxpool via MFMA 16x16x32 f16 (implicit GEMM)
// blocks [NIMG, NIMG+WCBLK): fc weight fp32->fp16 cast (overlaps with conv).
__global__ __launch_bounds__(256)
void prep(const float* __restrict__ X, const float* __restrict__ convw,
          const float* __restrict__ bias, _Float16* __restrict__ pooled,
          const float* __restrict__ fcw, _Float16* __restrict__ wh) {
    const int tid = threadIdx.x;
    if (blockIdx.x >= NIMG) {
        // ---- wcast part ----
        const size_t i = ((size_t)(blockIdx.x - NIMG) * 256 + tid) * 4;
        float4 v = *(const float4*)(fcw + i);
        v4hf o = {(_Float16)v.x, (_Float16)v.y, (_Float16)v.z, (_Float16)v.w};
        *(v4hf*)(wh + i) = o;
        return;
    }
    // ---- conv part: one block per image ----
    __shared__ _Float16 Xl[3 * 64 * 64 + 256];   // fp16 planes + pad (OOB-safe reads)
    __shared__ _Float16 Wl[32 * 32];             // [oc][k], k padded to 32 with zeros
    const int img = blockIdx.x;
    const float* xb = X + (size_t)img * (3 * IH * IW);
#pragma unroll
    for (int i = 0; i < 12; i++) {
        const int e = tid + i * 256;             // float4 index 0..3071
        float4 v = *(const float4*)(xb + (size_t)e * 4);
        h2 p0 = __builtin_amdgcn_cvt_pkrtz(v.x, v.y);   // same RTZ as old kernel
        h2 p1 = __builtin_amdgcn_cvt_pkrtz(v.z, v.w);
        *(h2*)&Xl[e * 4] = p0;
        *(h2*)&Xl[e * 4 + 2] = p1;
    }
    for (int t = tid; t < 1024; t += 256) {
        const int oc = t >> 5, k = t & 31;
        Wl[t] = (k < 27) ? (_Float16)convw[oc * 27 + k] : (_Float16)0.f;
    }
    __syncthreads();

    const int lane = tid & 63;
    const int l16 = lane & 15, q = lane >> 4;
    const int wv = tid >> 6;                     // wave 0..3
    // weight fragments: lane l16 = oc row, k = q*8+j
    v8hf a0 = *(const v8hf*)&Wl[l16 * 32 + q * 8];
    v8hf a1 = *(const v8hf*)&Wl[(16 + l16) * 32 + q * 8];
    // per-lane k -> LDS offset table (static indices only)
    int off[8];
#pragma unroll
    for (int j = 0; j < 8; j++) {
        const int k = q * 8 + j;
        const int c = k / 9, rem = k - c * 9;
        const int ky = rem / 3, kx = rem - ky * 3;
        off[j] = c * 4096 + ky * 64 + kx;        // k>=27 -> lands in pad region
    }
    const bool hi_ok = (q < 3);                  // j>=3 valid only for quads 0..2
    float b0r[4], b1r[4];
#pragma unroll
    for (int i = 0; i < 4; i++) {
        b0r[i] = bias[q * 4 + i];
        b1r[i] = bias[16 + q * 4 + i];
    }
    _Float16* outp = pooled + (size_t)img * FDIM;

    for (int oy = wv; oy < PH; oy += 4) {
        const int y0 = oy * 2;
#pragma unroll
        for (int xt = 0; xt < 4; xt++) {
            const int x = xt * 16 + l16;
            const int base0 = y0 * 64 + x;
            v8hf bf0, bf1;
#pragma unroll
            for (int j = 0; j < 8; j++) {
                _Float16 h0 = Xl[base0 + off[j]];
                _Float16 h1 = Xl[base0 + 64 + off[j]];
                if (j >= 3 && !hi_ok) { h0 = (_Float16)0.f; h1 = (_Float16)0.f; }
                bf0[j] = h0; bf1[j] = h1;
            }
            v4f c00 = (v4f)(0.f), c10 = (v4f)(0.f), c01 = (v4f)(0.f), c11 = (v4f)(0.f);
            c00 = __builtin_amdgcn_mfma_f32_16x16x32_f16(a0, bf0, c00, 0, 0, 0);
            c10 = __builtin_amdgcn_mfma_f32_16x16x32_f16(a1, bf0, c10, 0, 0, 0);
            c01 = __builtin_amdgcn_mfma_f32_16x16x32_f16(a0, bf1, c01, 0, 0, 0);
            c11 = __builtin_amdgcn_mfma_f32_16x16x32_f16(a1, bf1, c11, 0, 0, 0);
            const int ox = xt * 8 + (l16 >> 1);
            const bool act = ((l16 & 1) == 0) && (ox < PW);
#pragma unroll
            for (int i = 0; i < 4; i++) {
                float m0 = fmaxf(c00[i], c01[i]);          // y-pool, oc tile 0
                float m1 = fmaxf(c10[i], c11[i]);          // y-pool, oc tile 1
                m0 = fmaxf(m0, __shfl_xor(m0, 1));         // x-pool
                m1 = fmaxf(m1, __shfl_xor(m1, 1));
                if (act) {
                    const int oc0 = q * 4 + i;
                    const float r0 = fmaxf(m0 + b0r[i], 0.f);
                    const float r1 = fmaxf(m1 + b1r[i], 0.f);
                    outp[(size_t)oc0 * NPOS + oy * PW + ox] = (_Float16)r0;
                    outp[(size_t)(16 + oc0) * NPOS + oy * PW + ox] = (_Float16)r1;
                }
            }
        }
    }
}

// ---------------- K2: FC GEMM fp16 MFMA, 128x128 tile, split-K=31 ----------------
// R10-proven reg-staged body (R11 explicit prefetch was neutral -> reverted).
// NEW: XCD pair-swizzle. 1-D grid; decode so the two blocks sharing an A-panel
// (y=0/1 of the same (x,z)) have ids congruent mod 8 -> same XCD under round-robin
// dispatch -> the 254KB A-panel is fetched to that XCD's L2 once, second block hits.
// Pure index remap: correctness unaffected if the dispatch heuristic is wrong.
__global__ __launch_bounds__(256)
void fc_gemm(const _Float16* __restrict__ Ah, const _Float16* __restrict__ Wh,
             float* __restrict__ fpart) {
    // decode swizzled id: bid = (g%8) + 8*(2*(g/8) + y), g = x + 12*z in [0,372)
    const int bid = blockIdx.x;
    const int grp = bid >> 3;
    const int y = grp & 1;
    const int g = (bid & 7) + ((grp >> 1) << 3);
    if (g >= 372) return;                        // 8 padding holes
    const int xb = g % 12, zb = g / 12;

    __shared__ _Float16 Asl[128 * 56];
    __shared__ _Float16 Bsl[128 * 56];
    const int m0 = xb * 128, n0 = y * 128;
    const int k0 = zb * KCHE;
    const int tid = threadIdx.x;
    const int wave = tid >> 6, lane = tid & 63;
    const int quad = lane >> 4, l16 = lane & 15;
    const int wm = (wave & 1) * 64, wn = (wave >> 1) * 64;
    const int ar = tid >> 1, ac = (tid & 1) * 16;   // row 0..127, halves [ac,ac+16)
    const _Float16* Ag = Ah + (size_t)(m0 + ar) * FDIM + ac;
    const _Float16* Bg = Wh + (size_t)(n0 + ar) * FDIM + ac;

    v4f acc[4][4];
#pragma unroll
    for (int i = 0; i < 4; i++)
#pragma unroll
        for (int j = 0; j < 4; j++) acc[i][j] = (v4f)(0.f);

    for (int s = 0; s < KCHE / 32; s++) {
        const int gk = k0 + (s << 5);
        uint4 a0 = *(const uint4*)(Ag + gk);
        uint4 a1 = *(const uint4*)(Ag + gk + 8);
        uint4 b0 = *(const uint4*)(Bg + gk);
        uint4 b1 = *(const uint4*)(Bg + gk + 8);
        __syncthreads();
        *(uint4*)&Asl[ar * 56 + ac] = a0;
        *(uint4*)&Asl[ar * 56 + ac + 8] = a1;
        *(uint4*)&Bsl[ar * 56 + ac] = b0;
        *(uint4*)&Bsl[ar * 56 + ac + 8] = b1;
        __syncthreads();
        v8hf af[4], bf[4];
#pragma unroll
        for (int mt = 0; mt < 4; mt++)
            af[mt] = *(const v8hf*)&Asl[(wm + mt * 16 + l16) * 56 + quad * 8];
#pragma unroll
        for (int nt = 0; nt < 4; nt++)
            bf[nt] = *(const v8hf*)&Bsl[(wn + nt * 16 + l16) * 56 + quad * 8];
#pragma unroll
        for (int mt = 0; mt < 4; mt++)
#pragma unroll
            for (int nt = 0; nt < 4; nt++)
                acc[mt][nt] = __builtin_amdgcn_mfma_f32_16x16x32_f16(
                    af[mt], bf[nt], acc[mt][nt], 0, 0, 0);
    }
    float* outz = fpart + (size_t)zb * NIMG * FF;
#pragma unroll
    for (int mt = 0; mt < 4; mt++)
#pragma unroll
        for (int nt = 0; nt < 4; nt++)
#pragma unroll
            for (int i = 0; i < 4; i++) {
                const int gm = m0 + wm + mt * 16 + quad * 4 + i;
                const int gn = n0 + wn + nt * 16 + l16;
                outz[(size_t)gm * FF + gn] = acc[mt][nt][i];
            }
}

// ---------------- K2b: sum 31 split-K partials + bias + relu + fused row-norms ----------------
__global__ __launch_bounds__(256)
void bias_sum_relu(const float* __restrict__ fpart, const float* __restrict__ bias,
                   float* __restrict__ f, float* __restrict__ n2) {
    const int tid = threadIdx.x;
    const size_t idx = ((size_t)blockIdx.x * 256 + tid) * 4;
    float4 s = make_float4(0.f, 0.f, 0.f, 0.f);
#pragma unroll
    for (int z = 0; z < KSPLIT; z++) {
        float4 v = *(const float4*)(fpart + (size_t)z * NIMG * FF + idx);
        s.x += v.x; s.y += v.y; s.z += v.z; s.w += v.w;
    }
    const int col = (int)(idx & (FF - 1));
    float4 bv = *(const float4*)(bias + col);
    float4 o;
    o.x = fmaxf(s.x + bv.x, 0.f);
    o.y = fmaxf(s.y + bv.y, 0.f);
    o.z = fmaxf(s.z + bv.z, 0.f);
    o.w = fmaxf(s.w + bv.w, 0.f);
    *(float4*)(f + idx) = o;
    // fused rownorm: wave w of this block owns row blockIdx.x*4 + w
    float sq = o.x * o.x + o.y * o.y + o.z * o.z + o.w * o.w;
#pragma unroll
    for (int mm = 32; mm >= 1; mm >>= 1) sq += __shfl_xor(sq, mm);
    if ((tid & 63) == 0) n2[blockIdx.x * 4 + (tid >> 6)] = sq;
}

// ---------------- K3b: D = clamp(n2_i + n2_j - 2<f_i,f_j>, 0) + bar zeroing ----------------
// Blocks (0,0,b) also zero ot's counter line for batch b — replaces the separate
// hipMemsetAsync dispatch (dmat always precedes ot on the stream).
__global__ __launch_bounds__(256)
void dmat(const float* __restrict__ feats, const float* __restrict__ n2,
          float* __restrict__ Dm, unsigned* __restrict__ bar) {
    const int i0 = blockIdx.x * 16, j0 = blockIdx.y * 16, b = blockIdx.z;
    const int tid = threadIdx.x;
    if (blockIdx.x == 0 && blockIdx.y == 0 && tid < 64)
        __hip_atomic_store(&bar[b * 64 + tid], 0u, __ATOMIC_RELAXED,
                           __HIP_MEMORY_SCOPE_AGENT);
    __shared__ float fi[16][260], fj[16][260];
    const int r = tid >> 4, c0 = (tid & 15) * 16;
    const float* fbase = feats + (size_t)b * SS * FF;
#pragma unroll
    for (int v = 0; v < 16; v += 4) {
        float4 a = *(const float4*)(fbase + (size_t)(i0 + r) * FF + c0 + v);
        float4 w = *(const float4*)(fbase + (size_t)(j0 + r) * FF + c0 + v);
        *(float4*)&fi[r][c0 + v] = a;
        *(float4*)&fj[r][c0 + v] = w;
    }
    __syncthreads();
    const int ti = tid >> 4, tj = tid & 15;
    float dot = 0.f;
#pragma unroll 4
    for (int f = 0; f < FF; f += 4) {
        float4 a = *(const float4*)&fi[ti][f];
        float4 w = *(const float4*)&fj[tj][f];
        dot += a.x * w.x + a.y * w.y + a.z * w.z + a.w * w.w;
    }
    const int i = i0 + ti, j = j0 + tj;
    const float d = n2[b * SS + i] + n2[b * SS + j] - 2.f * dot;
    Dm[((size_t)b * SS + i) * SS + j] = fmaxf(d, 0.f);
}

// ---------------- K4: robust-OT solve, v9 (PROVEN 269.5us): R6 XCD-colocation + 3-barrier collect/publish ----------------
// Protocol converged after 6 variants (counter RMW + 1-line poll + bulk read;
// XCD-colocated mapping; merged collect+publish). Do not touch.
__global__ __launch_bounds__(512)
void ot_kernel(const float* __restrict__ Dg, const float* __restrict__ Qg,
               const float* __restrict__ thetag, float* __restrict__ ppub,
               unsigned* __restrict__ bar, float* __restrict__ out) {
    const int bk = blockIdx.x;
    const int b = bk % BB, k = bk / BB;      // XCD-colocating remap (R6, proven)
    const int tid = threadIdx.x;
    const int hw = tid >> 5, l = tid & 31;

    __shared__ float ppart[16][SS];
    __shared__ float cpart[16];
    __shared__ float Msh[SS];
    __shared__ float pown[SS];
    __shared__ float lamsh;

    float a[6][3], e[6][3], dre[6][3], rz[6], qi[6];

    const float* Db = Dg + (size_t)b * SS * SS;
    const float* Qb = Qg + ((size_t)b * KK + k) * SS;
#pragma unroll
    for (int r = 0; r < 6; r++) {
        const int i = hw * 6 + r;
#pragma unroll
        for (int u = 0; u < 3; u++) dre[r][u] = Db[i * SS + l + 32 * u];
        qi[r] = Qb[i];
    }
    const float th = thetag[k];
    unsigned* ctr = bar + b * 64;
    unsigned target = 0;

    // collect partials into pown, publish into buffer `buf`, drain, close barrier.
    auto collect_publish = [&](int buf) {
        __syncthreads();
        if (tid < SS) {
            float s = 0.f;
#pragma unroll
            for (int h = 0; h < 16; h++) s += ppart[h][tid];
            pown[tid] = s;
            __hip_atomic_store(&ppub[(((size_t)buf * BB + b) * KK + k) * SS + tid],
                               s, __ATOMIC_RELAXED, __HIP_MEMORY_SCOPE_AGENT);
        }
        if (tid == 0) {
            float c = 0.f;
#pragma unroll
            for (int h = 0; h < 16; h++) c += cpart[h];
            lamsh = 2.f * RHOC * fmaxf(c - th, 0.f);
        }
        asm volatile("s_waitcnt vmcnt(0)" ::: "memory");   // drain publish stores
        __syncthreads();                                    // all waves drained
    };

    // announce arrival + wait for all 10 blocks of this b-group.
    auto wait_group = [&]() {
        target += KK;
        if (tid == 0) {
            __hip_atomic_fetch_add(ctr, 1u, __ATOMIC_RELAXED, __HIP_MEMORY_SCOPE_AGENT);
            while (__hip_atomic_load(ctr, __ATOMIC_RELAXED, __HIP_MEMORY_SCOPE_AGENT) < target)
                __builtin_amdgcn_s_sleep(2);
        }
        __syncthreads();
    };

    {
        float cd[6];
#pragma unroll
        for (int r = 0; r < 6; r++) {
#pragma unroll
            for (int u = 0; u < 3; u++) { a[r][u] = 0.f; e[r][u] = 1.f; }
            rz[r] = 1.f / 96.f;
            cd[r] = dre[r][0] + dre[r][1] + dre[r][2];
        }
#pragma unroll
        for (int mm = 16; mm >= 1; mm >>= 1)
#pragma unroll
            for (int r = 0; r < 6; r++) cd[r] += __shfl_xor(cd[r], mm);
        float pp0 = 0.f, cc = 0.f;
#pragma unroll
        for (int r = 0; r < 6; r++) {
            const float scale = qi[r] * rz[r];
            pp0 += scale;
            cc += scale * cd[r];
        }
        ppart[hw][l] = pp0; ppart[hw][l + 32] = pp0; ppart[hw][l + 64] = pp0;
        if (l == 0) cpart[hw] = cc;
        collect_publish(0);
        wait_group();
    }

    for (int t = 0; t < NSTEPS; t++) {
        const int rbuf = t & 1;
        if (tid < SS) {
            const float* ps = ppub + (((size_t)rbuf * BB + b) * KK) * SS + tid;
            float v[KK];
            float mx = -1e30f;
#pragma unroll
            for (int kk2 = 0; kk2 < KK; kk2++) {
                v[kk2] = __hip_atomic_load(&ps[kk2 * SS], __ATOMIC_RELAXED,
                                           __HIP_MEMORY_SCOPE_AGENT) * TAUI;
                mx = fmaxf(mx, v[kk2]);
            }
            float sum = 0.f;
#pragma unroll
            for (int kk2 = 0; kk2 < KK; kk2++) sum += __expf(v[kk2] - mx);
            Msh[tid] = __expf(v[k] - mx) * __builtin_amdgcn_rcpf(sum);
        }
        __syncthreads();
        const float lam = lamsh;
        const float M0 = Msh[l], M1 = Msh[l + 32], M2 = Msh[l + 64];

        float g[6][3], dt[6];
#pragma unroll
        for (int r = 0; r < 6; r++) {
            g[r][0] = fmaf(lam, dre[r][0], M0);
            g[r][1] = fmaf(lam, dre[r][1], M1);
            g[r][2] = fmaf(lam, dre[r][2], M2);
            dt[r] = (e[r][0] * g[r][0] + e[r][1] * g[r][1] + e[r][2] * g[r][2]) * rz[r];
        }
#pragma unroll
        for (int mm = 16; mm >= 1; mm >>= 1)
#pragma unroll
            for (int r = 0; r < 6; r++) dt[r] += __shfl_xor(dt[r], mm);

        float mrow[6];
#pragma unroll
        for (int r = 0; r < 6; r++) {
            const float cq = LRC * qi[r] * rz[r];
            a[r][0] -= cq * e[r][0] * (g[r][0] - dt[r]);
            a[r][1] -= cq * e[r][1] * (g[r][1] - dt[r]);
            a[r][2] -= cq * e[r][2] * (g[r][2] - dt[r]);
            mrow[r] = fmaxf(a[r][0], fmaxf(a[r][1], a[r][2]));
        }
#pragma unroll
        for (int mm = 16; mm >= 1; mm >>= 1)
#pragma unroll
            for (int r = 0; r < 6; r++) mrow[r] = fmaxf(mrow[r], __shfl_xor(mrow[r], mm));

        float zz[6], cd[6];
#pragma unroll
        for (int r = 0; r < 6; r++) {
            e[r][0] = __expf(a[r][0] - mrow[r]);
            e[r][1] = __expf(a[r][1] - mrow[r]);
            e[r][2] = __expf(a[r][2] - mrow[r]);
            zz[r] = e[r][0] + e[r][1] + e[r][2];
            cd[r] = e[r][0] * dre[r][0] + e[r][1] * dre[r][1] + e[r][2] * dre[r][2];
        }
#pragma unroll
        for (int mm = 16; mm >= 1; mm >>= 1)
#pragma unroll
            for (int r = 0; r < 6; r++) {
                zz[r] += __shfl_xor(zz[r], mm);
                cd[r] += __shfl_xor(cd[r], mm);
            }

        float pp0 = 0.f, pp1 = 0.f, pp2 = 0.f, cc = 0.f;
#pragma unroll
        for (int r = 0; r < 6; r++) {
            const float rzz = __builtin_amdgcn_rcpf(zz[r]);
            rz[r] = rzz;
            const float scale = qi[r] * rzz;
            pp0 += scale * e[r][0];
            pp1 += scale * e[r][1];
            pp2 += scale * e[r][2];
            cc += scale * cd[r];
        }
        ppart[hw][l] = pp0; ppart[hw][l + 32] = pp1; ppart[hw][l + 64] = pp2;
        if (l == 0) cpart[hw] = cc;
        collect_publish((t + 1) & 1);   // final iter's store is dead but harmless
        if (t < NSTEPS - 1) wait_group();
    }
    if (tid < SS) out[((size_t)b * KK + k) * SS + tid] = pown[tid];
}

// ---------------- launch ----------------
extern "C" void kernel_launch(void* const* d_in, const int* in_sizes, int n_in,
                              void* d_out, int out_size, void* d_ws, size_t ws_size,
                              hipStream_t stream) {
    const float* X     = (const float*)d_in[0];
    const float* Q     = (const float*)d_in[1];
    const float* convw = (const float*)d_in[2];
    const float* convb = (const float*)d_in[3];
    const float* fcw   = (const float*)d_in[4];
    const float* fcb   = (const float*)d_in[5];
    const float* theta = (const float*)d_in[6];
    float* out = (float*)d_out;

    char* ws = (char*)d_ws;
    size_t off = 0;
    auto take = [&](size_t nbytes) {
        char* p = ws + off;
        off += (nbytes + 255) & ~(size_t)255;
        return (void*)p;
    };
    _Float16* pooled = (_Float16*)take((size_t)NIMG * FDIM * 2);       // 94.5 MB
    _Float16* Wh     = (_Float16*)take((size_t)FF * FDIM * 2);         // 15.7 MB
    float*    fpart  = (float*)take((size_t)KSPLIT * NIMG * FF * 4);   // 48.8 MB
    float*    feats  = (float*)take((size_t)NIMG * FF * 4);
    float*    n2     = (float*)take((size_t)NIMG * 4);
    float*    Dm     = (float*)take((size_t)BB * SS * SS * 4);
    float*    ppub   = (float*)take((size_t)2 * BB * KK * SS * 4);
    unsigned* bar    = (unsigned*)take((size_t)BB * 64 * 4);

    hipLaunchKernelGGL(prep, dim3(NIMG + WCBLK), dim3(256), 0, stream,
                       X, convw, convb, pooled, fcw, Wh);
    hipLaunchKernelGGL(fc_gemm, dim3(FCGRID), dim3(256), 0, stream, pooled, Wh, fpart);
    hipLaunchKernelGGL(bias_sum_relu, dim3(NIMG * FF / 1024), dim3(256), 0, stream,
                       fpart, fcb, feats, n2);
    hipLaunchKernelGGL(dmat, dim3(6, 6, BB), dim3(256), 0, stream, feats, n2, Dm, bar);
    hipLaunchKernelGGL(ot_kernel, dim3(BB * KK), dim3(512), 0, stream, Dm, Q, theta, ppub, bar, out);
}